// Round 19
// baseline (191.703 us; speedup 1.0000x reference)
//
#include <hip/hip_runtime.h>
#include <math.h>

typedef short bf16x8 __attribute__((ext_vector_type(8)));
typedef float f32x4 __attribute__((ext_vector_type(4)));
typedef unsigned short u16x8 __attribute__((ext_vector_type(8)));
typedef unsigned short u16x4 __attribute__((ext_vector_type(4)));

// Segments (cu_seqlens=[0,1024,2560,4096], searchsorted side='left'):
// seg0 [0,1025) len1025 ; seg1 [1025,2561) len1536 ; seg2 [2561,4096) len1535
// vT packed cols: pc(s) = s<1025 ? s : s+63 (seg0 @0 pad->1088, seg1 @1088, seg2 @2624); width 4160

__device__ __forceinline__ unsigned short f2b(float f) {
  union { float f; unsigned int u; } v; v.f = f;
  unsigned int u = v.u;
  return (unsigned short)((u + 0x7FFFu + ((u >> 16) & 1u)) >> 16);  // RTNE
}
__device__ __forceinline__ float b2f(unsigned short h) {
  union { unsigned int u; float f; } v; v.u = ((unsigned int)h) << 16; return v.f;
}

// raw barrier: waits LDS ops only (NOT vmcnt) -> attn stores never drained in-loop
__device__ __forceinline__ void barrier_lds() {
  asm volatile("s_waitcnt lgkmcnt(0)" ::: "memory");
  __builtin_amdgcn_sched_barrier(0);
  __builtin_amdgcn_s_barrier();
}

// ---- merged prep: cvt | rope tables | vT pad | twcvt(qkv) | twcvt(proj) ----
__device__ __forceinline__ void twcvt_body(const float* __restrict__ src, unsigned short* __restrict__ dst,
                                           int K, int N, int k0, int n0, int t, float (&tile)[32][33]) {
  for (int i = 0; i < 4; i++) {
    int e = t + i * 256; int r = e >> 5, c = e & 31;
    tile[r][c] = src[(size_t)(k0 + r) * N + n0 + c];
  }
  __syncthreads();
  for (int i = 0; i < 4; i++) {
    int e = t + i * 256; int r = e >> 5, c = e & 31;
    dst[(size_t)(n0 + r) * K + k0 + c] = f2b(tile[c][r]);
  }
}

__global__ __launch_bounds__(256) void k_prep(const float* __restrict__ x, unsigned short* __restrict__ xb,
                                              float* __restrict__ cosT, float* __restrict__ sinT,
                                              unsigned short* __restrict__ vT,
                                              const float* __restrict__ qkv_w, unsigned short* __restrict__ wqkvT,
                                              const float* __restrict__ proj_w, unsigned short* __restrict__ wprojT) {
  __shared__ float tile[32][33];
  int bid = blockIdx.x, t = threadIdx.x;
  if (bid < 2048) {
    int idx = bid * 256 + t;
    float4 v = ((const float4*)x)[idx];
    ushort4 o; o.x = f2b(v.x); o.y = f2b(v.y); o.z = f2b(v.z); o.w = f2b(v.w);
    ((ushort4*)xb)[idx] = o;
  } else if (bid < 2560) {
    int idx = (bid - 2048) * 256 + t;
    int pos = idx >> 5, i = idx & 31;
    float invf = (float)(1.0 / pow(10000.0, (double)i / 32.0));
    float ang = (float)pos * invf;
    cosT[idx] = cosf(ang);
    sinT[idx] = sinf(ang);
  } else if (bid < 2568) {
    int h = bid - 2560;
    for (int i = t; i < 64 * 64; i += 256) {
      int d = i >> 6, c = i & 63;
      vT[((size_t)(h * 64 + d)) * 4160 + 1024 + c] = 0;
    }
    if (t < 64) vT[((size_t)(h * 64 + t)) * 4160 + 4159] = 0;
  } else if (bid < 3336) {
    int i = bid - 2568;
    twcvt_body(qkv_w, wqkvT, 512, 1536, (i & 15) * 32, (i >> 4) * 32, t, tile);
  } else {
    int i = bid - 3336;
    twcvt_body(proj_w, wprojT, 512, 512, (i & 15) * 32, (i >> 4) * 32, t, tile);
  }
}

// ---- generic NT GEMM, BK=128 ----
__global__ __launch_bounds__(256) void k_gemm(const unsigned short* __restrict__ A,
                                              const unsigned short* __restrict__ Bt,
                                              const float* __restrict__ bias,
                                              float* __restrict__ C,
                                              int M, int N, int K) {
  __shared__ unsigned short As[2][64][72];
  __shared__ unsigned short Bs[2][64][72];
  int row0 = blockIdx.x * 64, col0 = blockIdx.y * 64;
  int t = threadIdx.x, w = t >> 6, l = t & 63;
  int l15 = l & 15, l4 = l >> 4;
  f32x4 acc[4] = {};
  for (int k0 = 0; k0 < K; k0 += 128) {
    for (int i = 0; i < 2; i++) {
      int e = t + i * 256; int r = e >> 3, c8 = e & 7;
      *(uint4*)&As[0][r][c8 * 8] = *(const uint4*)(A + (size_t)(row0 + r) * K + k0 + c8 * 8);
      *(uint4*)&Bs[0][r][c8 * 8] = *(const uint4*)(Bt + (size_t)(col0 + r) * K + k0 + c8 * 8);
      *(uint4*)&As[1][r][c8 * 8] = *(const uint4*)(A + (size_t)(row0 + r) * K + k0 + 64 + c8 * 8);
      *(uint4*)&Bs[1][r][c8 * 8] = *(const uint4*)(Bt + (size_t)(col0 + r) * K + k0 + 64 + c8 * 8);
    }
    __syncthreads();
    for (int h = 0; h < 2; h++)
      for (int kh = 0; kh < 2; kh++) {
        bf16x8 a = *(const bf16x8*)&As[h][w * 16 + l15][kh * 32 + l4 * 8];
        for (int cf = 0; cf < 4; cf++) {
          bf16x8 b = *(const bf16x8*)&Bs[h][cf * 16 + l15][kh * 32 + l4 * 8];
          acc[cf] = __builtin_amdgcn_mfma_f32_16x16x32_bf16(a, b, acc[cf], 0, 0, 0);
        }
      }
    __syncthreads();
  }
  for (int cf = 0; cf < 4; cf++) {
    int col = col0 + cf * 16 + l15;
    float bv = bias[col];
    for (int r = 0; r < 4; r++) {
      int row = row0 + w * 16 + l4 * 4 + r;
      C[(size_t)row * N + col] = acc[cf][r] + bv;
    }
  }
}

// ---- qkv GEMM (K=512, BK=128) with fused bias + RoPE + head-split + V-transpose ----
__global__ __launch_bounds__(256) void k_gemm_qkv(const unsigned short* __restrict__ A,
                                                  const unsigned short* __restrict__ Bt,
                                                  const float* __restrict__ bias,
                                                  const float* __restrict__ cosT,
                                                  const float* __restrict__ sinT,
                                                  unsigned short* __restrict__ qh,
                                                  unsigned short* __restrict__ kh,
                                                  unsigned short* __restrict__ vT) {
  __shared__ unsigned short As[2][64][72];
  __shared__ unsigned short Bs[2][64][72];
  int row0 = blockIdx.x * 64, col0 = blockIdx.y * 64;
  int t = threadIdx.x, w = t >> 6, l = t & 63;
  int l15 = l & 15, l4 = l >> 4;
  f32x4 acc[4] = {};
  for (int k0 = 0; k0 < 512; k0 += 128) {
    for (int i = 0; i < 2; i++) {
      int e = t + i * 256; int r = e >> 3, c8 = e & 7;
      *(uint4*)&As[0][r][c8 * 8] = *(const uint4*)(A + (size_t)(row0 + r) * 512 + k0 + c8 * 8);
      *(uint4*)&Bs[0][r][c8 * 8] = *(const uint4*)(Bt + (size_t)(col0 + r) * 512 + k0 + c8 * 8);
      *(uint4*)&As[1][r][c8 * 8] = *(const uint4*)(A + (size_t)(row0 + r) * 512 + k0 + 64 + c8 * 8);
      *(uint4*)&Bs[1][r][c8 * 8] = *(const uint4*)(Bt + (size_t)(col0 + r) * 512 + k0 + 64 + c8 * 8);
    }
    __syncthreads();
    for (int hh = 0; hh < 2; hh++)
      for (int kk = 0; kk < 2; kk++) {
        bf16x8 a = *(const bf16x8*)&As[hh][w * 16 + l15][kk * 32 + l4 * 8];
        for (int cf = 0; cf < 4; cf++) {
          bf16x8 b = *(const bf16x8*)&Bs[hh][cf * 16 + l15][kk * 32 + l4 * 8];
          acc[cf] = __builtin_amdgcn_mfma_f32_16x16x32_bf16(a, b, acc[cf], 0, 0, 0);
        }
      }
    __syncthreads();
  }
  for (int cf = 0; cf < 4; cf++) {
    float bv = bias[col0 + cf * 16 + l15];
    for (int r = 0; r < 4; r++) acc[cf][r] += bv;
  }
  int kind = col0 >> 9;
  int h = (col0 & 511) >> 6;
  if (kind < 2) {
    for (int r = 0; r < 4; r++) {
      int row = row0 + w * 16 + l4 * 4 + r;
      float c0 = cosT[row * 32 + l15],      s0 = sinT[row * 32 + l15];
      float c1 = cosT[row * 32 + 16 + l15], s1 = sinT[row * 32 + 16 + l15];
      float q0 = acc[0][r], q1 = acc[1][r], q2 = acc[2][r], q3 = acc[3][r];
      int rl = w * 16 + l4 * 4 + r;
      As[0][rl][0 * 16 + l15] = f2b(q0 * c0 - q2 * s0);
      As[0][rl][1 * 16 + l15] = f2b(q1 * c1 - q3 * s1);
      As[0][rl][2 * 16 + l15] = f2b(q2 * c0 + q0 * s0);
      As[0][rl][3 * 16 + l15] = f2b(q3 * c1 + q1 * s1);
    }
  } else {
    for (int cf = 0; cf < 4; cf++)
      for (int r = 0; r < 4; r++)
        As[0][w * 16 + l4 * 4 + r][cf * 16 + l15] = f2b(acc[cf][r]);
  }
  __syncthreads();
  if (kind < 2) {
    unsigned short* dst = (kind == 0 ? qh : kh);
    for (int p = 0; p < 2; p++) {
      int idx = p * 256 + t;
      int rl = idx >> 3, c8 = (idx & 7) * 8;
      *(u16x8*)(dst + ((size_t)(h * 4096 + row0 + rl)) * 64 + c8) = *(const u16x8*)&As[0][rl][c8];
    }
  } else {
    for (int p = 0; p < 2; p++) {
      int idx = p * 256 + t;
      int d = idx >> 3, s8 = (idx & 7) * 8;
      int sbase = row0 + s8;
      u16x8 val;
      for (int j = 0; j < 8; j++) val[j] = As[0][s8 + j][d];
      unsigned short* vrow = vT + ((size_t)(h * 64 + d)) * 4160;
      if (sbase != 1024) {
        int pc = (sbase < 1025) ? sbase : sbase + 63;
        *(u16x8*)(vrow + pc) = val;
      } else {
        for (int j = 0; j < 8; j++) {
          int s = sbase + j;
          vrow[(s < 1025) ? s : s + 63] = val[j];
        }
      }
    }
  }
}

// ---- attention v11: producer/consumer wave specialization. 512 threads/block.
// Waves 0-3 (t<256): compute QK^T, denom, normalized-P into Sc ring, PV, opre.
// Waves 4-7: Phase A = stream ALL off-segment zeros; Phase B = drain Sc ring
// into valid-region quad stores, one tile behind. Barrier counts match per role:
// Phase A = NKT+1, Phase B = NKT+1.
template<int SEG>
__device__ __forceinline__ void attn_pc_body(int h, int row0,
    const unsigned short* __restrict__ qh, const unsigned short* __restrict__ kh,
    const unsigned short* __restrict__ vT, float* __restrict__ attn,
    unsigned short* __restrict__ opre,
    unsigned short (&Ks)[2][64][72], unsigned short (&Vt)[2][64][72],
    unsigned short (&Sc)[2][64][72], unsigned short (&carry63)[4][64]) {
  constexpr int LO  = SEG == 0 ? 0 : (SEG == 1 ? 1025 : 2561);
  constexpr int HI  = SEG == 0 ? 1025 : (SEG == 1 ? 2561 : 4096);
  constexpr int LEN = HI - LO;
  constexpr int NKT = SEG == 0 ? 17 : 24;
  constexpr int CS  = SEG == 0 ? 0 : (SEG == 1 ? 1088 : 2624);
  constexpr int CQ0 = LO & ~3;
  constexpr int DLO = LO - CQ0;         // 0 or 1
  constexpr int ZQ  = SEG == 0 ? 752 : (SEG == 1 ? 639 : 640);   // zero quads/row
  constexpr int QPTA = SEG == 0 ? 11 : 7;                        // zeros per lane per A-interval

  int t = threadIdx.x;
  float* abase = attn + ((size_t)h * 4096 + row0) * 4096;
  int nvalid = HI - row0; if (nvalid > 64) nvalid = 64;

  if (t < 256) {
    // ================= COMPUTE ROLE (waves 0-3) =================
    int w = t >> 6, l = t & 63, l15 = l & 15, l4 = l >> 4;
    int rw = w * 16;
    const unsigned short* kbase = kh + ((size_t)h * 4096) * 64;
    const unsigned short* vbase = vT + ((size_t)h * 64) * 4160 + CS;

    auto stageK = [&](int ct, int buf) {
      for (int i = 0; i < 2; i++) {
        int e = t + i * 256; int r = e >> 3, c8 = e & 7;
        int kr = LO + ct * 64 + r; if (kr > 4095) kr = 4095;
        *(uint4*)&Ks[buf][r][c8 * 8] = *(const uint4*)(kbase + (size_t)kr * 64 + c8 * 8);
      }
    };
    auto stageV = [&](int ct, int buf) {
      for (int i = 0; i < 2; i++) {
        int e = t + i * 256; int r = e >> 3, c8 = e & 7;
        *(uint4*)&Vt[buf][r][c8 * 8] = *(const uint4*)(vbase + (size_t)r * 4160 + ct * 64 + c8 * 8);
      }
    };

    bf16x8 qa[2];
    {
      int m = row0 + rw + l15; if (m > 4095) m = 4095;
      const unsigned short* qp = qh + ((size_t)(h * 4096 + m)) * 64;
      qa[0] = *(const bf16x8*)(qp + l4 * 8);
      qa[1] = *(const bf16x8*)(qp + 32 + l4 * 8);
    }

    // Phase A: NKT+1 barriers
    float rsum[4] = {0.f, 0.f, 0.f, 0.f};
    stageK(0, 0);
    barrier_lds();
    for (int ct = 0; ct < NKT; ct++) {
      if (ct + 1 < NKT) stageK(ct + 1, (ct + 1) & 1);
      f32x4 acc[4] = {};
      for (int kf = 0; kf < 2; kf++)
        for (int cf = 0; cf < 4; cf++) {
          bf16x8 b = *(const bf16x8*)&Ks[ct & 1][cf * 16 + l15][kf * 32 + l4 * 8];
          acc[cf] = __builtin_amdgcn_mfma_f32_16x16x32_bf16(qa[kf], b, acc[cf], 0, 0, 0);
        }
      for (int cf = 0; cf < 4; cf++) {
        int gc = ct * 64 + cf * 16 + l15;
        bool valid = gc < LEN;
        for (int r = 0; r < 4; r++)
          rsum[r] += valid ? __expf(acc[cf][r] * 0.125f) : 0.f;
      }
      barrier_lds();
    }
    float li[4];
    for (int r = 0; r < 4; r++) {
      float s = rsum[r];
      for (int o = 1; o < 16; o <<= 1) s += __shfl_xor(s, o, 16);
      li[r] = -__logf(s);
    }

    // Phase B: NKT+1 barriers. Sc[ct&1] published at barrier ending iter ct.
    f32x4 pacc[4] = {};
    stageK(0, 0); stageV(0, 0);
    barrier_lds();                       // b0
    for (int ct = 0; ct < NKT; ct++) {
      if (ct + 1 < NKT) { stageK(ct + 1, (ct + 1) & 1); stageV(ct + 1, (ct + 1) & 1); }
      f32x4 acc[4] = {};
      for (int kf = 0; kf < 2; kf++)
        for (int cf = 0; cf < 4; cf++) {
          bf16x8 b = *(const bf16x8*)&Ks[ct & 1][cf * 16 + l15][kf * 32 + l4 * 8];
          acc[cf] = __builtin_amdgcn_mfma_f32_16x16x32_bf16(qa[kf], b, acc[cf], 0, 0, 0);
        }
      for (int cf = 0; cf < 4; cf++)
        for (int r = 0; r < 4; r++) {
          unsigned short us = f2b(__expf(fmaf(acc[cf][r], 0.125f, li[r])));
          Sc[ct & 1][rw + l4 * 4 + r][cf * 16 + l15] = us;
          if (DLO == 1 && cf == 3 && l15 == 15)
            carry63[ct & 3][rw + l4 * 4 + r] = us;   // col 63 of each row
        }
      // PV on own just-written Sc (same-wave RAW)
      for (int kf = 0; kf < 2; kf++) {
        bf16x8 ap = *(const bf16x8*)&Sc[ct & 1][rw + l15][kf * 32 + l4 * 8];
        for (int cf = 0; cf < 4; cf++) {
          bf16x8 b = *(const bf16x8*)&Vt[ct & 1][cf * 16 + l15][kf * 32 + l4 * 8];
          pacc[cf] = __builtin_amdgcn_mfma_f32_16x16x32_bf16(ap, b, pacc[cf], 0, 0, 0);
        }
      }
      barrier_lds();                     // b_{ct+1}
    }
    for (int cf = 0; cf < 4; cf++)
      for (int r = 0; r < 4; r++) {
        int grow = row0 + rw + l4 * 4 + r;
        if (grow < HI)
          opre[(size_t)grow * 512 + h * 64 + cf * 16 + l15] = f2b(pacc[cf][r]);
      }
  } else {
    // ================= STORE ROLE (waves 4-7) =================
    int tc = t - 256;
    int cw = tc >> 6, l = tc & 63;
    int Z = nvalid * ZQ;
    float4 z4 = make_float4(0.f, 0.f, 0.f, 0.f);

    // Phase A: stream all zeros; NKT+1 barriers
    int zc = tc;
    for (int it = 0; it < NKT + 1; it++) {
      for (int j = 0; j < QPTA; j++) {
        int z = zc; zc += 256;
        if (z < Z) {
          int row = z / ZQ, qi = z - row * ZQ;
          int q = SEG == 0 ? qi + 272 : (SEG == 1 ? (qi < 256 ? qi : qi + 385) : qi);
          *(float4*)(abase + (size_t)row * 4096 + q * 4) = z4;
        }
      }
      barrier_lds();
    }

    // Phase B: drain Sc ring; NKT+1 barriers (b0 + one per tile)
    barrier_lds();                       // b0
    for (int ct = 0; ct < NKT; ct++) {
      barrier_lds();                     // b_{ct+1}: Sc[ct&1] now published
      for (int j = 0; j < 4; j++) {
        int rowL = cw * 16 + j * 4 + (l >> 4), qt = l & 15;
        int grow = row0 + rowL;
        u16x4 q = *(const u16x4*)&Sc[ct & 1][rowL][qt * 4];
        float f0 = b2f(q[0]), f1 = b2f(q[1]), f2 = b2f(q[2]), f3 = b2f(q[3]);
        float4 o;
        if (DLO == 1) {
          float prev = __shfl_up(f3, 1, 16);
          if (qt == 0) prev = (ct > 0) ? b2f(carry63[(ct - 1) & 3][rowL]) : 0.f;
          int cb = ct * 64 + qt * 4 - 1;
          o.x = prev;
          o.y = (cb + 1 < LEN) ? f0 : 0.f;
          o.z = (cb + 2 < LEN) ? f1 : 0.f;
          o.w = (cb + 3 < LEN) ? f2 : 0.f;
        } else {
          int cb = ct * 64 + qt * 4;
          o.x = (cb + 0 < LEN) ? f0 : 0.f;
          o.y = (cb + 1 < LEN) ? f1 : 0.f;
          o.z = (cb + 2 < LEN) ? f2 : 0.f;
          o.w = (cb + 3 < LEN) ? f3 : 0.f;
        }
        if (grow < HI)
          *(float4*)(abase + (size_t)rowL * 4096 + CQ0 + ct * 64 + qt * 4) = o;
      }
    }
    if (SEG == 1 && tc < 64) {           // final col 2560 from last carry
      int grow = row0 + tc;
      if (grow < HI) {
        float v = b2f(carry63[(NKT - 1) & 3][tc]);
        *(float4*)(abase + (size_t)tc * 4096 + 2560) = make_float4(v, 0.f, 0.f, 0.f);
      }
    }
  }
}

__global__ __launch_bounds__(512, 4) void k_attn11(const unsigned short* __restrict__ qh,
                                                   const unsigned short* __restrict__ kh,
                                                   const unsigned short* __restrict__ vT,
                                                   float* __restrict__ attn,
                                                   unsigned short* __restrict__ opre) {
  __shared__ unsigned short Ks[2][64][72];
  __shared__ unsigned short Vt[2][64][72];
  __shared__ unsigned short Sc[2][64][72];
  __shared__ unsigned short carry63[4][64];
  int bid = blockIdx.x;                 // 520 = 65 strips x 8 heads
  int h = bid & 7, st = bid >> 3;
  if (st < 17)      attn_pc_body<0>(h, st * 64,               qh, kh, vT, attn, opre, Ks, Vt, Sc, carry63);
  else if (st < 41) attn_pc_body<1>(h, 1025 + (st - 17) * 64, qh, kh, vT, attn, opre, Ks, Vt, Sc, carry63);
  else              attn_pc_body<2>(h, 2561 + (st - 41) * 64, qh, kh, vT, attn, opre, Ks, Vt, Sc, carry63);
}

extern "C" void kernel_launch(void* const* d_in, const int* in_sizes, int n_in,
                              void* d_out, int out_size, void* d_ws, size_t ws_size,
                              hipStream_t stream) {
  const float* hidden = (const float*)d_in[0];
  const float* qkv_w  = (const float*)d_in[1];
  const float* qkv_b  = (const float*)d_in[2];
  const float* proj_w = (const float*)d_in[3];
  const float* proj_b = (const float*)d_in[4];

  char* p = (char*)d_ws;
  auto alloc = [&](size_t bytes) { char* r = p; p += (bytes + 255) & ~(size_t)255; return r; };
  float*          cosT   = (float*)alloc((size_t)4096 * 32 * 4);
  float*          sinT   = (float*)alloc((size_t)4096 * 32 * 4);
  unsigned short* xb     = (unsigned short*)alloc((size_t)4096 * 512 * 2);
  unsigned short* wqkvT  = (unsigned short*)alloc((size_t)1536 * 512 * 2);
  unsigned short* wprojT = (unsigned short*)alloc((size_t)512 * 512 * 2);
  unsigned short* qhb    = (unsigned short*)alloc((size_t)8 * 4096 * 64 * 2);
  unsigned short* khb    = (unsigned short*)alloc((size_t)8 * 4096 * 64 * 2);
  unsigned short* vTb    = (unsigned short*)alloc((size_t)8 * 64 * 4160 * 2);
  unsigned short* opre   = (unsigned short*)alloc((size_t)4096 * 512 * 2);

  float* final_out = (float*)d_out;                       // [4096][512]
  float* attn_out  = (float*)d_out + (size_t)4096 * 512;  // [8][4096][4096]

  k_prep<<<dim3(3592), dim3(256), 0, stream>>>(hidden, xb, cosT, sinT, vTb,
                                               qkv_w, wqkvT, proj_w, wprojT);
  k_gemm_qkv<<<dim3(64, 24), dim3(256), 0, stream>>>(xb, wqkvT, qkv_b, cosT, sinT, qhb, khb, vTb);
  k_attn11<<<dim3(520), dim3(512), 0, stream>>>(qhb, khb, vTb, attn_out, opre);
  k_gemm<<<dim3(64, 8), dim3(256), 0, stream>>>(opre, wprojT, proj_b, final_out, 4096, 512, 512);
}

// Round 20
// 168.285 us; speedup vs baseline: 1.1392x; 1.1392x over previous
//
#include <hip/hip_runtime.h>
#include <math.h>

typedef short bf16x8 __attribute__((ext_vector_type(8)));
typedef float f32x4 __attribute__((ext_vector_type(4)));
typedef unsigned short u16x8 __attribute__((ext_vector_type(8)));
typedef unsigned short u16x4 __attribute__((ext_vector_type(4)));

// Segments (cu_seqlens=[0,1024,2560,4096], searchsorted side='left'):
// seg0 [0,1025) len1025 ; seg1 [1025,2561) len1536 ; seg2 [2561,4096) len1535
// vT packed cols: pc(s) = s<1025 ? s : s+63 (seg0 @0 pad->1088, seg1 @1088, seg2 @2624); width 4160

__device__ __forceinline__ unsigned short f2b(float f) {
  union { float f; unsigned int u; } v; v.f = f;
  unsigned int u = v.u;
  return (unsigned short)((u + 0x7FFFu + ((u >> 16) & 1u)) >> 16);  // RTNE
}
__device__ __forceinline__ float b2f(unsigned short h) {
  union { unsigned int u; float f; } v; v.u = ((unsigned int)h) << 16; return v.f;
}

// raw barrier: waits LDS ops only (NOT vmcnt) -> attn stores are never drained in-loop
__device__ __forceinline__ void barrier_lds() {
  asm volatile("s_waitcnt lgkmcnt(0)" ::: "memory");
  __builtin_amdgcn_sched_barrier(0);
  __builtin_amdgcn_s_barrier();
}

// ---- merged prep: cvt | rope tables | vT pad | twcvt(qkv) | twcvt(proj) ----
__device__ __forceinline__ void twcvt_body(const float* __restrict__ src, unsigned short* __restrict__ dst,
                                           int K, int N, int k0, int n0, int t, float (&tile)[32][33]) {
  for (int i = 0; i < 4; i++) {
    int e = t + i * 256; int r = e >> 5, c = e & 31;
    tile[r][c] = src[(size_t)(k0 + r) * N + n0 + c];
  }
  __syncthreads();
  for (int i = 0; i < 4; i++) {
    int e = t + i * 256; int r = e >> 5, c = e & 31;
    dst[(size_t)(n0 + r) * K + k0 + c] = f2b(tile[c][r]);
  }
}

__global__ __launch_bounds__(256) void k_prep(const float* __restrict__ x, unsigned short* __restrict__ xb,
                                              float* __restrict__ cosT, float* __restrict__ sinT,
                                              unsigned short* __restrict__ vT,
                                              const float* __restrict__ qkv_w, unsigned short* __restrict__ wqkvT,
                                              const float* __restrict__ proj_w, unsigned short* __restrict__ wprojT) {
  __shared__ float tile[32][33];
  int bid = blockIdx.x, t = threadIdx.x;
  if (bid < 2048) {                     // f32 -> bf16 convert of hidden (524288 float4)
    int idx = bid * 256 + t;
    float4 v = ((const float4*)x)[idx];
    ushort4 o; o.x = f2b(v.x); o.y = f2b(v.y); o.z = f2b(v.z); o.w = f2b(v.w);
    ((ushort4*)xb)[idx] = o;
  } else if (bid < 2560) {              // RoPE tables (4096*32)
    int idx = (bid - 2048) * 256 + t;
    int pos = idx >> 5, i = idx & 31;
    float invf = (float)(1.0 / pow(10000.0, (double)i / 32.0));
    float ang = (float)pos * invf;
    cosT[idx] = cosf(ang);
    sinT[idx] = sinf(ang);
  } else if (bid < 2568) {              // vT pad columns
    int h = bid - 2560;
    for (int i = t; i < 64 * 64; i += 256) {
      int d = i >> 6, c = i & 63;
      vT[((size_t)(h * 64 + d)) * 4160 + 1024 + c] = 0;
    }
    if (t < 64) vT[((size_t)(h * 64 + t)) * 4160 + 4159] = 0;
  } else if (bid < 3336) {              // transpose+cvt qkv_w [512][1536] -> [1536][512]
    int i = bid - 2568;
    twcvt_body(qkv_w, wqkvT, 512, 1536, (i & 15) * 32, (i >> 4) * 32, t, tile);
  } else {                              // transpose+cvt proj_w [512][512] -> [512][512]
    int i = bid - 3336;
    twcvt_body(proj_w, wprojT, 512, 512, (i & 15) * 32, (i >> 4) * 32, t, tile);
  }
}

// ---- generic NT GEMM, BK=128 (two 64-chunks per barrier pair), K%128==0 ----
__global__ __launch_bounds__(256) void k_gemm(const unsigned short* __restrict__ A,
                                              const unsigned short* __restrict__ Bt,
                                              const float* __restrict__ bias,
                                              float* __restrict__ C,
                                              int M, int N, int K) {
  __shared__ unsigned short As[2][64][72];
  __shared__ unsigned short Bs[2][64][72];
  int row0 = blockIdx.x * 64, col0 = blockIdx.y * 64;
  int t = threadIdx.x, w = t >> 6, l = t & 63;
  int l15 = l & 15, l4 = l >> 4;
  f32x4 acc[4] = {};
  for (int k0 = 0; k0 < K; k0 += 128) {
    for (int i = 0; i < 2; i++) {
      int e = t + i * 256; int r = e >> 3, c8 = e & 7;
      *(uint4*)&As[0][r][c8 * 8] = *(const uint4*)(A + (size_t)(row0 + r) * K + k0 + c8 * 8);
      *(uint4*)&Bs[0][r][c8 * 8] = *(const uint4*)(Bt + (size_t)(col0 + r) * K + k0 + c8 * 8);
      *(uint4*)&As[1][r][c8 * 8] = *(const uint4*)(A + (size_t)(row0 + r) * K + k0 + 64 + c8 * 8);
      *(uint4*)&Bs[1][r][c8 * 8] = *(const uint4*)(Bt + (size_t)(col0 + r) * K + k0 + 64 + c8 * 8);
    }
    __syncthreads();
    for (int h = 0; h < 2; h++)
      for (int kh = 0; kh < 2; kh++) {
        bf16x8 a = *(const bf16x8*)&As[h][w * 16 + l15][kh * 32 + l4 * 8];
        for (int cf = 0; cf < 4; cf++) {
          bf16x8 b = *(const bf16x8*)&Bs[h][cf * 16 + l15][kh * 32 + l4 * 8];
          acc[cf] = __builtin_amdgcn_mfma_f32_16x16x32_bf16(a, b, acc[cf], 0, 0, 0);
        }
      }
    __syncthreads();
  }
  for (int cf = 0; cf < 4; cf++) {
    int col = col0 + cf * 16 + l15;
    float bv = bias[col];
    for (int r = 0; r < 4; r++) {
      int row = row0 + w * 16 + l4 * 4 + r;
      C[(size_t)row * N + col] = acc[cf][r] + bv;
    }
  }
}

// ---- qkv GEMM (K=512, BK=128) with fused bias + RoPE + head-split + V-transpose ----
__global__ __launch_bounds__(256) void k_gemm_qkv(const unsigned short* __restrict__ A,
                                                  const unsigned short* __restrict__ Bt,
                                                  const float* __restrict__ bias,
                                                  const float* __restrict__ cosT,
                                                  const float* __restrict__ sinT,
                                                  unsigned short* __restrict__ qh,
                                                  unsigned short* __restrict__ kh,
                                                  unsigned short* __restrict__ vT) {
  __shared__ unsigned short As[2][64][72];
  __shared__ unsigned short Bs[2][64][72];
  int row0 = blockIdx.x * 64, col0 = blockIdx.y * 64;
  int t = threadIdx.x, w = t >> 6, l = t & 63;
  int l15 = l & 15, l4 = l >> 4;
  f32x4 acc[4] = {};
  for (int k0 = 0; k0 < 512; k0 += 128) {
    for (int i = 0; i < 2; i++) {
      int e = t + i * 256; int r = e >> 3, c8 = e & 7;
      *(uint4*)&As[0][r][c8 * 8] = *(const uint4*)(A + (size_t)(row0 + r) * 512 + k0 + c8 * 8);
      *(uint4*)&Bs[0][r][c8 * 8] = *(const uint4*)(Bt + (size_t)(col0 + r) * 512 + k0 + c8 * 8);
      *(uint4*)&As[1][r][c8 * 8] = *(const uint4*)(A + (size_t)(row0 + r) * 512 + k0 + 64 + c8 * 8);
      *(uint4*)&Bs[1][r][c8 * 8] = *(const uint4*)(Bt + (size_t)(col0 + r) * 512 + k0 + 64 + c8 * 8);
    }
    __syncthreads();
    for (int hh = 0; hh < 2; hh++)
      for (int kk = 0; kk < 2; kk++) {
        bf16x8 a = *(const bf16x8*)&As[hh][w * 16 + l15][kk * 32 + l4 * 8];
        for (int cf = 0; cf < 4; cf++) {
          bf16x8 b = *(const bf16x8*)&Bs[hh][cf * 16 + l15][kk * 32 + l4 * 8];
          acc[cf] = __builtin_amdgcn_mfma_f32_16x16x32_bf16(a, b, acc[cf], 0, 0, 0);
        }
      }
    __syncthreads();
  }
  for (int cf = 0; cf < 4; cf++) {
    float bv = bias[col0 + cf * 16 + l15];
    for (int r = 0; r < 4; r++) acc[cf][r] += bv;
  }
  int kind = col0 >> 9;                 // 0=q, 1=k, 2=v
  int h = (col0 & 511) >> 6;
  if (kind < 2) {
    for (int r = 0; r < 4; r++) {
      int row = row0 + w * 16 + l4 * 4 + r;
      float c0 = cosT[row * 32 + l15],      s0 = sinT[row * 32 + l15];
      float c1 = cosT[row * 32 + 16 + l15], s1 = sinT[row * 32 + 16 + l15];
      float q0 = acc[0][r], q1 = acc[1][r], q2 = acc[2][r], q3 = acc[3][r];
      int rl = w * 16 + l4 * 4 + r;
      As[0][rl][0 * 16 + l15] = f2b(q0 * c0 - q2 * s0);
      As[0][rl][1 * 16 + l15] = f2b(q1 * c1 - q3 * s1);
      As[0][rl][2 * 16 + l15] = f2b(q2 * c0 + q0 * s0);
      As[0][rl][3 * 16 + l15] = f2b(q3 * c1 + q1 * s1);
    }
  } else {
    for (int cf = 0; cf < 4; cf++)
      for (int r = 0; r < 4; r++)
        As[0][w * 16 + l4 * 4 + r][cf * 16 + l15] = f2b(acc[cf][r]);
  }
  __syncthreads();
  if (kind < 2) {
    unsigned short* dst = (kind == 0 ? qh : kh);
    for (int p = 0; p < 2; p++) {
      int idx = p * 256 + t;
      int rl = idx >> 3, c8 = (idx & 7) * 8;
      *(u16x8*)(dst + ((size_t)(h * 4096 + row0 + rl)) * 64 + c8) = *(const u16x8*)&As[0][rl][c8];
    }
  } else {
    for (int p = 0; p < 2; p++) {
      int idx = p * 256 + t;
      int d = idx >> 3, s8 = (idx & 7) * 8;
      int sbase = row0 + s8;
      u16x8 val;
      for (int j = 0; j < 8; j++) val[j] = As[0][s8 + j][d];
      unsigned short* vrow = vT + ((size_t)(h * 64 + d)) * 4160;
      if (sbase != 1024) {
        int pc = (sbase < 1025) ? sbase : sbase + 63;
        *(u16x8*)(vrow + pc) = val;
      } else {
        for (int j = 0; j < 8; j++) {
          int s = sbase + j;
          vrow[(s < 1025) ? s : s + 63] = val[j];
        }
      }
    }
  }
}

// ---- fused attention (best-known): 64-row strips, wave-owned rows, lgkmcnt-only
// barriers, double-buffered K/V staging, normalized-P in Sc, aligned u16x4 quad
// readback with shfl carry.
template<int SEG>
__device__ __forceinline__ void attn_body7(int h, int row0,
    const unsigned short* __restrict__ qh, const unsigned short* __restrict__ kh,
    const unsigned short* __restrict__ vT, float* __restrict__ attn,
    unsigned short* __restrict__ opre,
    unsigned short (&Ks)[2][64][72], unsigned short (&Vt)[2][64][72],
    unsigned short (&Sc)[64][72], unsigned short (&carry63)[2][64]) {
  constexpr int LO  = SEG == 0 ? 0 : (SEG == 1 ? 1025 : 2561);
  constexpr int HI  = SEG == 0 ? 1025 : (SEG == 1 ? 2561 : 4096);
  constexpr int LEN = HI - LO;
  constexpr int NKT = SEG == 0 ? 17 : 24;
  constexpr int CS  = SEG == 0 ? 0 : (SEG == 1 ? 1088 : 2624);
  constexpr int CQ0 = LO & ~3;          // aligned quad base of covered region
  constexpr int DLO = LO - CQ0;         // 0 or 1
  constexpr int ZQ  = SEG == 0 ? 752 : (SEG == 1 ? 639 : 640);  // zero quads/row
  constexpr int QPT = SEG == 0 ? 6 : 4; // zero quads per thread per step (2*NKT steps)

  int t = threadIdx.x, w = t >> 6, l = t & 63, l15 = l & 15, l4 = l >> 4;
  int rw = w * 16;                      // wave-owned rows

  int nvalid = HI - row0; if (nvalid > 64) nvalid = 64;
  int Z = nvalid * ZQ;
  int zc = t;
  float* abase = attn + ((size_t)h * 4096 + row0) * 4096;
  float4 z4 = make_float4(0.f, 0.f, 0.f, 0.f);

  auto zero_step = [&]() {
    for (int j = 0; j < QPT; j++) {
      int z = zc; zc += 256;
      if (z < Z) {
        int row = z / ZQ, qi = z - row * ZQ;
        int q = SEG == 0 ? qi + 272 : (SEG == 1 ? (qi < 256 ? qi : qi + 385) : qi);
        *(float4*)(abase + (size_t)row * 4096 + q * 4) = z4;
      }
    }
  };

  const unsigned short* kbase = kh + ((size_t)h * 4096) * 64;
  const unsigned short* vbase = vT + ((size_t)h * 64) * 4160 + CS;

  auto stageK = [&](int ct, int buf) {
    for (int i = 0; i < 2; i++) {
      int e = t + i * 256; int r = e >> 3, c8 = e & 7;
      int kr = LO + ct * 64 + r; if (kr > 4095) kr = 4095;
      *(uint4*)&Ks[buf][r][c8 * 8] = *(const uint4*)(kbase + (size_t)kr * 64 + c8 * 8);
    }
  };
  auto stageV = [&](int ct, int buf) {
    for (int i = 0; i < 2; i++) {
      int e = t + i * 256; int r = e >> 3, c8 = e & 7;
      *(uint4*)&Vt[buf][r][c8 * 8] = *(const uint4*)(vbase + (size_t)r * 4160 + ct * 64 + c8 * 8);
    }
  };

  bf16x8 qa[2];
  {
    int m = row0 + rw + l15; if (m > 4095) m = 4095;
    const unsigned short* qp = qh + ((size_t)(h * 4096 + m)) * 64;
    qa[0] = *(const bf16x8*)(qp + l4 * 8);
    qa[1] = *(const bf16x8*)(qp + 32 + l4 * 8);
  }

  // ---- Phase A: row sums of exp(s*0.125), K staged, 1 barrier/iter ----
  float rsum[4] = {0.f, 0.f, 0.f, 0.f};
  stageK(0, 0);
  barrier_lds();
  for (int ct = 0; ct < NKT; ct++) {
    if (ct + 1 < NKT) stageK(ct + 1, (ct + 1) & 1);
    zero_step();
    f32x4 acc[4] = {};
    for (int kf = 0; kf < 2; kf++)
      for (int cf = 0; cf < 4; cf++) {
        bf16x8 b = *(const bf16x8*)&Ks[ct & 1][cf * 16 + l15][kf * 32 + l4 * 8];
        acc[cf] = __builtin_amdgcn_mfma_f32_16x16x32_bf16(qa[kf], b, acc[cf], 0, 0, 0);
      }
    for (int cf = 0; cf < 4; cf++) {
      int gc = ct * 64 + cf * 16 + l15;
      bool valid = gc < LEN;
      for (int r = 0; r < 4; r++)
        rsum[r] += valid ? __expf(acc[cf][r] * 0.125f) : 0.f;
    }
    barrier_lds();
  }
  // li[r] = -log(rowsum): per-lane row constant
  float li[4];
  for (int r = 0; r < 4; r++) {
    float s = rsum[r];
    for (int o = 1; o < 16; o <<= 1) s += __shfl_xor(s, o, 16);
    li[r] = -__logf(s);
  }

  // aligned quad stores of tile ct: Sc holds NORMALIZED bf16 P
  auto store_quads = [&](int ct) {
    for (int j = 0; j < 4; j++) {
      int idx = j * 64 + l;
      int rowL = rw + (idx >> 4), qt = idx & 15;
      int grow = row0 + rowL;
      u16x4 q = *(const u16x4*)&Sc[rowL][qt * 4];   // aligned 8B LDS read
      float f0 = b2f(q[0]), f1 = b2f(q[1]), f2 = b2f(q[2]), f3 = b2f(q[3]);
      float4 o;
      if (DLO == 1) {
        float prev = __shfl_up(f3, 1, 16);          // neighbor lane's last elem (same row group)
        if (qt == 0) prev = (ct > 0) ? b2f(carry63[(ct - 1) & 1][rowL]) : 0.f;
        int cb = ct * 64 + qt * 4 - 1;
        o.x = prev;                                  // cb always < LEN for DLO segs
        o.y = (cb + 1 < LEN) ? f0 : 0.f;
        o.z = (cb + 2 < LEN) ? f1 : 0.f;
        o.w = (cb + 3 < LEN) ? f2 : 0.f;
      } else {
        int cb = ct * 64 + qt * 4;
        o.x = (cb + 0 < LEN) ? f0 : 0.f;
        o.y = (cb + 1 < LEN) ? f1 : 0.f;
        o.z = (cb + 2 < LEN) ? f2 : 0.f;
        o.w = (cb + 3 < LEN) ? f3 : 0.f;
      }
      if (grow < HI)
        *(float4*)(abase + (size_t)rowL * 4096 + CQ0 + ct * 64 + qt * 4) = o;
    }
  };

  // ---- Phase B: normalized scores -> Sc (wave rows); quad stores; PV. 1 barrier/iter ----
  f32x4 pacc[4] = {};
  stageK(0, 0); stageV(0, 0);
  barrier_lds();
  for (int ct = 0; ct < NKT; ct++) {
    if (ct + 1 < NKT) { stageK(ct + 1, (ct + 1) & 1); stageV(ct + 1, (ct + 1) & 1); }
    zero_step();
    f32x4 acc[4] = {};
    for (int kf = 0; kf < 2; kf++)
      for (int cf = 0; cf < 4; cf++) {
        bf16x8 b = *(const bf16x8*)&Ks[ct & 1][cf * 16 + l15][kf * 32 + l4 * 8];
        acc[cf] = __builtin_amdgcn_mfma_f32_16x16x32_bf16(qa[kf], b, acc[cf], 0, 0, 0);
      }
    for (int cf = 0; cf < 4; cf++)
      for (int r = 0; r < 4; r++)
        Sc[rw + l4 * 4 + r][cf * 16 + l15] = f2b(__expf(fmaf(acc[cf][r], 0.125f, li[r])));
    store_quads(ct);
    if (DLO == 1 && l < 16) carry63[ct & 1][rw + l] = Sc[rw + l][63];  // wave-owned
    // PV (Sc rows are this wave's; P already normalized)
    for (int kf = 0; kf < 2; kf++) {
      bf16x8 ap = *(const bf16x8*)&Sc[rw + l15][kf * 32 + l4 * 8];
      for (int cf = 0; cf < 4; cf++) {
        bf16x8 b = *(const bf16x8*)&Vt[ct & 1][cf * 16 + l15][kf * 32 + l4 * 8];
        pacc[cf] = __builtin_amdgcn_mfma_f32_16x16x32_bf16(ap, b, pacc[cf], 0, 0, 0);
      }
    }
    barrier_lds();
  }
  if (SEG == 1 && l < 16) {             // final col 2560 (gc=1535) from last carry
    int rowL = rw + l, grow = row0 + rowL;
    if (grow < HI) {
      float v = b2f(carry63[(NKT - 1) & 1][rowL]);
      *(float4*)(abase + (size_t)rowL * 4096 + 2560) = make_float4(v, 0.f, 0.f, 0.f);
    }
  }

  for (int cf = 0; cf < 4; cf++)
    for (int r = 0; r < 4; r++) {
      int grow = row0 + rw + l4 * 4 + r;
      if (grow < HI)
        opre[(size_t)grow * 512 + h * 64 + cf * 16 + l15] = f2b(pacc[cf][r]);
    }
}

__global__ __launch_bounds__(256, 3) void k_attn7(const unsigned short* __restrict__ qh,
                                                  const unsigned short* __restrict__ kh,
                                                  const unsigned short* __restrict__ vT,
                                                  float* __restrict__ attn,
                                                  unsigned short* __restrict__ opre) {
  __shared__ unsigned short Ks[2][64][72];
  __shared__ unsigned short Vt[2][64][72];
  __shared__ unsigned short Sc[64][72];
  __shared__ unsigned short carry63[2][64];
  int bid = blockIdx.x;                 // 520 = 65 strips x 8 heads; h = bid&7 -> head per XCD
  int h = bid & 7, st = bid >> 3;
  if (st < 17)      attn_body7<0>(h, st * 64,               qh, kh, vT, attn, opre, Ks, Vt, Sc, carry63);
  else if (st < 41) attn_body7<1>(h, 1025 + (st - 17) * 64, qh, kh, vT, attn, opre, Ks, Vt, Sc, carry63);
  else              attn_body7<2>(h, 2561 + (st - 41) * 64, qh, kh, vT, attn, opre, Ks, Vt, Sc, carry63);
}

extern "C" void kernel_launch(void* const* d_in, const int* in_sizes, int n_in,
                              void* d_out, int out_size, void* d_ws, size_t ws_size,
                              hipStream_t stream) {
  const float* hidden = (const float*)d_in[0];
  const float* qkv_w  = (const float*)d_in[1];
  const float* qkv_b  = (const float*)d_in[2];
  const float* proj_w = (const float*)d_in[3];
  const float* proj_b = (const float*)d_in[4];

  char* p = (char*)d_ws;
  auto alloc = [&](size_t bytes) { char* r = p; p += (bytes + 255) & ~(size_t)255; return r; };
  float*          cosT   = (float*)alloc((size_t)4096 * 32 * 4);
  float*          sinT   = (float*)alloc((size_t)4096 * 32 * 4);
  unsigned short* xb     = (unsigned short*)alloc((size_t)4096 * 512 * 2);
  unsigned short* wqkvT  = (unsigned short*)alloc((size_t)1536 * 512 * 2);
  unsigned short* wprojT = (unsigned short*)alloc((size_t)512 * 512 * 2);
  unsigned short* qhb    = (unsigned short*)alloc((size_t)8 * 4096 * 64 * 2);
  unsigned short* khb    = (unsigned short*)alloc((size_t)8 * 4096 * 64 * 2);
  unsigned short* vTb    = (unsigned short*)alloc((size_t)8 * 64 * 4160 * 2);
  unsigned short* opre   = (unsigned short*)alloc((size_t)4096 * 512 * 2);

  float* final_out = (float*)d_out;                       // [4096][512]
  float* attn_out  = (float*)d_out + (size_t)4096 * 512;  // [8][4096][4096]

  k_prep<<<dim3(3592), dim3(256), 0, stream>>>(hidden, xb, cosT, sinT, vTb,
                                               qkv_w, wqkvT, proj_w, wprojT);
  k_gemm_qkv<<<dim3(64, 24), dim3(256), 0, stream>>>(xb, wqkvT, qkv_b, cosT, sinT, qhb, khb, vTb);
  k_attn7<<<dim3(520), dim3(256), 0, stream>>>(qhb, khb, vTb, attn_out, opre);
  k_gemm<<<dim3(64, 8), dim3(256), 0, stream>>>(opre, wprojT, proj_b, final_out, 4096, 512, 512);
}